// Round 10
// baseline (140.300 us; speedup 1.0000x reference)
//
#include <hip/hip_runtime.h>

#define LLEN 65536
#define CIN 64
#define COUT 64
#define LTILE 1024   // l positions per block (256 threads x 4)

typedef float f32x4 __attribute__((ext_vector_type(4)));
typedef unsigned long long u64;

// Per-co constant record, 64 B so the co-loop fetch is one s_load_dwordx16.
struct __align__(64) WRec {
    u64 p0, p1, p2;                 // sign words (bit=1 iff w>0) for k=0,1,2
    float A;    // wscale * sum_nnz + bias
    float S;    // -2 * wscale
    float Bv, G, Z;                 // RPReLU beta, gamma, zeta
    float f0, f2;                   // 0.5*nnz(k=0), 0.5*nnz(k=2) edge fixups
    float pad[3];
};

__global__ void pack_weights(const float* __restrict__ w,
                             const float* __restrict__ wscale,
                             const float* __restrict__ bias,
                             const float* __restrict__ beta,
                             const float* __restrict__ gamma,
                             const float* __restrict__ zeta,
                             WRec* __restrict__ rec) {
    int co = threadIdx.x;
    if (co >= COUT) return;
    u64 p[3];
    int nnz[3], ntot = 0;
    for (int k = 0; k < 3; ++k) {
        u64 pos = 0ull, nz = 0ull;
        for (int ci = 0; ci < CIN; ++ci) {
            float wv = w[co * (CIN * 3) + ci * 3 + k];
            pos |= ((u64)(wv > 0.0f)) << ci;
            nz  |= ((u64)(wv != 0.0f)) << ci;
        }
        p[k] = pos;
        nnz[k] = __popcll(nz);
        ntot += nnz[k];
    }
    WRec r;
    float s = wscale[co];
    r.p0 = p[0]; r.p1 = p[1]; r.p2 = p[2];
    r.A  = s * (float)ntot + bias[co];
    r.S  = -2.0f * s;
    r.Bv = beta[co]; r.G = gamma[co]; r.Z = zeta[co];
    r.f0 = 0.5f * (float)nnz[0];
    r.f2 = 0.5f * (float)nnz[2];
    r.pad[0] = r.pad[1] = r.pad[2] = 0.0f;
    rec[co] = r;
}

__device__ __forceinline__ float rprelu(float y, float B, float G, float Z) {
    float xs = y - G;
    return (y > G) ? (xs + Z) : fmaf(B, xs, Z);
}

// EDGE: 0 = interior block, 1 = contains l==0, 2 = contains l==LLEN-1.
template <int EDGE>
__device__ __forceinline__ void co_loop(const WRec* __restrict__ rec,
                                        u64 xq0, u64 xq1, u64 xq2,
                                        u64 xq3, u64 xq4, u64 xq5,
                                        bool fixlane, float* __restrict__ outp) {
    #pragma unroll 4
    for (int co = 0; co < COUT; ++co) {
        const WRec r = rec[co];   // uniform address -> scalar loads
        float fx = (float)(__popcll(xq0 ^ r.p0) + __popcll(xq1 ^ r.p1)
                         + __popcll(xq2 ^ r.p2));
        float fy = (float)(__popcll(xq1 ^ r.p0) + __popcll(xq2 ^ r.p1)
                         + __popcll(xq3 ^ r.p2));
        float fz = (float)(__popcll(xq2 ^ r.p0) + __popcll(xq3 ^ r.p1)
                         + __popcll(xq4 ^ r.p2));
        float fw = (float)(__popcll(xq3 ^ r.p0) + __popcll(xq4 ^ r.p1)
                         + __popcll(xq5 ^ r.p2));
        if (EDGE == 1 && fixlane)   // l==0 (o.x): k=0 term is zero padding
            fx = (float)(__popcll(xq1 ^ r.p1) + __popcll(xq2 ^ r.p2)) + r.f0;
        if (EDGE == 2 && fixlane)   // l==LLEN-1 (o.w): k=2 term is zero padding
            fw = (float)(__popcll(xq3 ^ r.p0) + __popcll(xq4 ^ r.p1)) + r.f2;
        f32x4 o;
        o.x = rprelu(fmaf(r.S, fx, r.A), r.Bv, r.G, r.Z);
        o.y = rprelu(fmaf(r.S, fy, r.A), r.Bv, r.G, r.Z);
        o.z = rprelu(fmaf(r.S, fz, r.A), r.Bv, r.G, r.Z);
        o.w = rprelu(fmaf(r.S, fw, r.A), r.Bv, r.G, r.Z);
        *(f32x4*)(outp + (size_t)co * LLEN) = o;   // plain store: L2-buffered,
                                                   // decouples issue from HBM drain
    }
}

// ---------------------------------------------------------------------------
// Main kernel (best-known R6 structure): block = (batch b, 1024 l), thread
// owns 4 l, packed words staged in LDS, block-level halo via __ballot.
// R10 edits: (1) plain stores instead of nontemporal; (2) halo loads issued
// BEFORE the 64-row pack loop (ballot after), hiding their latency under the
// main load burst.
// ---------------------------------------------------------------------------
__global__ void __launch_bounds__(256, 4) bconv_kernel(
        const float* __restrict__ x,
        const float* __restrict__ alpha,
        const WRec* __restrict__ rec,
        float* __restrict__ out) {
    __shared__ u64 xw[LTILE + 2];   // xw[i] = word for l = lbase+i-1

    const int t = threadIdx.x;
    const int b = blockIdx.y;
    const int lbase = blockIdx.x * LTILE;
    const float* xrow = x + (size_t)b * CIN * LLEN;

    // Halo loads issued first (latency hidden under the pack burst).
    float vhalo = 0.0f;
    if (t < 64) {
        int l = lbase - 1;
        if (l >= 0) vhalo = xrow[(size_t)t * LLEN + l];
    } else if (t < 128) {
        int ci = t - 64;
        int l = lbase + LTILE;
        if (l < LLEN) vhalo = xrow[(size_t)ci * LLEN + l];
    }

    // Phase 1: pack. Thread t covers l = lbase+4t..+3 -> xw[4t+1 .. 4t+4]
    const float* xb = xrow + lbase + 4 * t;
    u64 w0 = 0, w1 = 0, w2 = 0, w3 = 0;
    #pragma unroll 16
    for (int ci = 0; ci < CIN; ++ci) {
        const f32x4 v = *(const f32x4*)(xb + (size_t)ci * LLEN);
        const float a = alpha[ci];                 // uniform -> s_load
        w0 |= ((u64)(v.x >= a)) << ci;
        w1 |= ((u64)(v.y >= a)) << ci;
        w2 |= ((u64)(v.z >= a)) << ci;
        w3 |= ((u64)(v.w >= a)) << ci;
    }
    xw[4 * t + 1] = w0;
    xw[4 * t + 2] = w1;
    xw[4 * t + 3] = w2;
    xw[4 * t + 4] = w3;

    // Halo ballots (loads long since landed).
    if (t < 64) {
        u64 word = __ballot(vhalo >= alpha[t]);
        if (t == 0) xw[0] = word;                  // garbage if lbase==0; EDGE=1 fixes
    } else if (t < 128) {
        int ci = t - 64;
        u64 word = __ballot(vhalo >= alpha[ci]);
        if (ci == 0) xw[LTILE + 1] = word;         // garbage if top; EDGE=2 fixes
    }
    __syncthreads();

    // Phase 2: window words for l = lbase+4t-1 .. +4
    const u64 xq0 = xw[4 * t + 0], xq1 = xw[4 * t + 1],
              xq2 = xw[4 * t + 2], xq3 = xw[4 * t + 3],
              xq4 = xw[4 * t + 4], xq5 = xw[4 * t + 5];
    float* outp = out + (size_t)b * COUT * LLEN + lbase + 4 * t;

    if (blockIdx.x == 0)
        co_loop<1>(rec, xq0, xq1, xq2, xq3, xq4, xq5, t == 0, outp);
    else if (blockIdx.x == gridDim.x - 1)
        co_loop<2>(rec, xq0, xq1, xq2, xq3, xq4, xq5, t == 255, outp);
    else
        co_loop<0>(rec, xq0, xq1, xq2, xq3, xq4, xq5, false, outp);
}

extern "C" void kernel_launch(void* const* d_in, const int* in_sizes, int n_in,
                              void* d_out, int out_size, void* d_ws, size_t ws_size,
                              hipStream_t stream) {
    const float* x      = (const float*)d_in[0];
    const float* alpha  = (const float*)d_in[1];
    const float* w      = (const float*)d_in[2];
    const float* wscale = (const float*)d_in[3];
    const float* bias   = (const float*)d_in[4];
    const float* beta   = (const float*)d_in[5];
    const float* gamma  = (const float*)d_in[6];
    const float* zeta   = (const float*)d_in[7];
    float* out = (float*)d_out;

    WRec* rec = (WRec*)d_ws;   // 64 * 64 B = 4 KB

    pack_weights<<<1, 64, 0, stream>>>(w, wscale, bias, beta, gamma, zeta, rec);

    dim3 grid(LLEN / LTILE, 16);
    bconv_kernel<<<grid, 256, 0, stream>>>(x, alpha, rec, out);
}

// Round 11
// 121.593 us; speedup vs baseline: 1.1538x; 1.1538x over previous
//
#include <hip/hip_runtime.h>

#define LLEN 65536
#define CIN 64
#define COUT 64
#define LTILE 1024   // l positions per block (256 threads x 4)

typedef float f32x4 __attribute__((ext_vector_type(4)));
typedef unsigned long long u64;

// bits layout in ws: per batch row of (LLEN+2) u64, index l+1 holds word(l).
// Pad entries [0] and [LLEN+1] are never written (EDGE fixups ignore them).
#define BROW (LLEN + 2)

// Per-co constant record, 64 B so the co-loop fetch is one s_load_dwordx16.
struct __align__(64) WRec {
    u64 p0, p1, p2;                 // sign words (bit=1 iff w>0) for k=0,1,2
    float A;    // wscale * sum_nnz + bias
    float S;    // -2 * wscale
    float Bv, G, Z;                 // RPReLU beta, gamma, zeta
    float f0, f2;                   // 0.5*nnz(k=0), 0.5*nnz(k=2) edge fixups
    float pad[3];
};

__global__ void pack_weights(const float* __restrict__ w,
                             const float* __restrict__ wscale,
                             const float* __restrict__ bias,
                             const float* __restrict__ beta,
                             const float* __restrict__ gamma,
                             const float* __restrict__ zeta,
                             WRec* __restrict__ rec) {
    int co = threadIdx.x;
    if (co >= COUT) return;
    u64 p[3];
    int nnz[3], ntot = 0;
    for (int k = 0; k < 3; ++k) {
        u64 pos = 0ull, nz = 0ull;
        for (int ci = 0; ci < CIN; ++ci) {
            float wv = w[co * (CIN * 3) + ci * 3 + k];
            pos |= ((u64)(wv > 0.0f)) << ci;
            nz  |= ((u64)(wv != 0.0f)) << ci;
        }
        p[k] = pos;
        nnz[k] = __popcll(nz);
        ntot += nnz[k];
    }
    WRec r;
    float s = wscale[co];
    r.p0 = p[0]; r.p1 = p[1]; r.p2 = p[2];
    r.A  = s * (float)ntot + bias[co];
    r.S  = -2.0f * s;
    r.Bv = beta[co]; r.G = gamma[co]; r.Z = zeta[co];
    r.f0 = 0.5f * (float)nnz[0];
    r.f2 = 0.5f * (float)nnz[2];
    r.pad[0] = r.pad[1] = r.pad[2] = 0.0f;
    rec[co] = r;
}

// ---------------------------------------------------------------------------
// Kernel A: pure streaming pack. Thread owns 4 l: 64 f32x4 strided reads ->
// 4 packed sign words -> one 32 B contiguous store. No LDS, no barrier.
// Single-direction read stream at the read ceiling; pack VALU hides under it.
// ---------------------------------------------------------------------------
__global__ void __launch_bounds__(256) pack_x(
        const float* __restrict__ x,
        const float* __restrict__ alpha,
        u64* __restrict__ bits) {
    const int t = threadIdx.x;
    const int b = blockIdx.y;
    const int l0 = blockIdx.x * LTILE + 4 * t;
    const float* xb = x + (size_t)b * CIN * LLEN + l0;

    u64 w0 = 0, w1 = 0, w2 = 0, w3 = 0;
    #pragma unroll 16
    for (int ci = 0; ci < CIN; ++ci) {
        const f32x4 v = *(const f32x4*)(xb + (size_t)ci * LLEN);
        const float a = alpha[ci];                 // uniform -> s_load
        w0 |= ((u64)(v.x >= a)) << ci;
        w1 |= ((u64)(v.y >= a)) << ci;
        w2 |= ((u64)(v.z >= a)) << ci;
        w3 |= ((u64)(v.w >= a)) << ci;
    }
    // bits[b][l+1] = word(l); 32 B contiguous per thread, coalesced per wave.
    u64* dst = bits + (size_t)b * BROW + l0 + 1;
    dst[0] = w0; dst[1] = w1; dst[2] = w2; dst[3] = w3;
}

__device__ __forceinline__ float rprelu(float y, float B, float G, float Z) {
    float xs = y - G;
    return (y > G) ? (xs + Z) : fmaf(B, xs, Z);
}

// EDGE: 0 = interior block, 1 = contains l==0, 2 = contains l==LLEN-1.
template <int EDGE>
__device__ __forceinline__ void co_loop(const WRec* __restrict__ rec,
                                        u64 xq0, u64 xq1, u64 xq2,
                                        u64 xq3, u64 xq4, u64 xq5,
                                        bool fixlane, float* __restrict__ outp) {
    #pragma unroll 4
    for (int co = 0; co < COUT; ++co) {
        const WRec r = rec[co];   // uniform address -> scalar loads
        float fx = (float)(__popcll(xq0 ^ r.p0) + __popcll(xq1 ^ r.p1)
                         + __popcll(xq2 ^ r.p2));
        float fy = (float)(__popcll(xq1 ^ r.p0) + __popcll(xq2 ^ r.p1)
                         + __popcll(xq3 ^ r.p2));
        float fz = (float)(__popcll(xq2 ^ r.p0) + __popcll(xq3 ^ r.p1)
                         + __popcll(xq4 ^ r.p2));
        float fw = (float)(__popcll(xq3 ^ r.p0) + __popcll(xq4 ^ r.p1)
                         + __popcll(xq5 ^ r.p2));
        if (EDGE == 1 && fixlane)   // l==0 (o.x): k=0 term is zero padding
            fx = (float)(__popcll(xq1 ^ r.p1) + __popcll(xq2 ^ r.p2)) + r.f0;
        if (EDGE == 2 && fixlane)   // l==LLEN-1 (o.w): k=2 term is zero padding
            fw = (float)(__popcll(xq3 ^ r.p0) + __popcll(xq4 ^ r.p1)) + r.f2;
        f32x4 o;
        o.x = rprelu(fmaf(r.S, fx, r.A), r.Bv, r.G, r.Z);
        o.y = rprelu(fmaf(r.S, fy, r.A), r.Bv, r.G, r.Z);
        o.z = rprelu(fmaf(r.S, fz, r.A), r.Bv, r.G, r.Z);
        o.w = rprelu(fmaf(r.S, fw, r.A), r.Bv, r.G, r.Z);
        __builtin_nontemporal_store(o, (f32x4*)(outp + (size_t)co * LLEN));
    }
}

// ---------------------------------------------------------------------------
// Kernel B: compute + stream out. Thread owns 4 l: loads its 6-word window
// from the L3-resident bits array (48 B), runs the 64-co loop, nt stores.
// Single-direction write stream at the write ceiling; VALU hides under it.
// ---------------------------------------------------------------------------
__global__ void __launch_bounds__(256) bconv_compute(
        const u64* __restrict__ bits,
        const WRec* __restrict__ rec,
        float* __restrict__ out) {
    const int t = threadIdx.x;
    const int b = blockIdx.y;
    const int l0 = blockIdx.x * LTILE + 4 * t;

    // window words for l = l0-1 .. l0+4  ->  bits[b][l0 .. l0+5]
    const u64* src = bits + (size_t)b * BROW + l0;
    const u64 xq0 = src[0], xq1 = src[1], xq2 = src[2],
              xq3 = src[3], xq4 = src[4], xq5 = src[5];

    float* outp = out + (size_t)b * COUT * LLEN + l0;

    if (blockIdx.x == 0)
        co_loop<1>(rec, xq0, xq1, xq2, xq3, xq4, xq5, t == 0, outp);
    else if (blockIdx.x == gridDim.x - 1)
        co_loop<2>(rec, xq0, xq1, xq2, xq3, xq4, xq5, t == 255, outp);
    else
        co_loop<0>(rec, xq0, xq1, xq2, xq3, xq4, xq5, false, outp);
}

extern "C" void kernel_launch(void* const* d_in, const int* in_sizes, int n_in,
                              void* d_out, int out_size, void* d_ws, size_t ws_size,
                              hipStream_t stream) {
    const float* x      = (const float*)d_in[0];
    const float* alpha  = (const float*)d_in[1];
    const float* w      = (const float*)d_in[2];
    const float* wscale = (const float*)d_in[3];
    const float* bias   = (const float*)d_in[4];
    const float* beta   = (const float*)d_in[5];
    const float* gamma  = (const float*)d_in[6];
    const float* zeta   = (const float*)d_in[7];
    float* out = (float*)d_out;

    // ws layout: [0, 4KB) WRec[64]; [4KB, 4KB + 16*BROW*8) packed bits.
    WRec* rec = (WRec*)d_ws;
    u64* bits = (u64*)((char*)d_ws + 4096);

    pack_weights<<<1, 64, 0, stream>>>(w, wscale, bias, beta, gamma, zeta, rec);

    dim3 grid(LLEN / LTILE, 16);
    pack_x<<<grid, 256, 0, stream>>>(x, alpha, bits);
    bconv_compute<<<grid, 256, 0, stream>>>(bits, rec, out);
}

// Round 12
// 104.888 us; speedup vs baseline: 1.3376x; 1.1593x over previous
//
#include <hip/hip_runtime.h>

#define LLEN 65536
#define CIN 64
#define COUT 64

typedef float f32x2 __attribute__((ext_vector_type(2)));
typedef float f32x4 __attribute__((ext_vector_type(4)));
typedef unsigned long long u64;

// bits layout in ws: per batch row of (LLEN+2) u64, index l+1 holds word(l).
// Pad entries [0] and [LLEN+1] are never written (EDGE fixups handle them).
#define BROW (LLEN + 2)

// Per-co constant record, 64 B so the per-block fetch is one s_load_dwordx16.
struct __align__(64) WRec {
    u64 p0, p1, p2;                 // sign words (bit=1 iff w>0) for k=0,1,2
    float A;    // wscale * sum_nnz + bias
    float S;    // -2 * wscale
    float Bv, G, Z;                 // RPReLU beta, gamma, zeta
    float f0, f2;                   // 0.5*nnz(k=0), 0.5*nnz(k=2) edge fixups
    float pad[3];
};

__global__ void pack_weights(const float* __restrict__ w,
                             const float* __restrict__ wscale,
                             const float* __restrict__ bias,
                             const float* __restrict__ beta,
                             const float* __restrict__ gamma,
                             const float* __restrict__ zeta,
                             WRec* __restrict__ rec) {
    int co = threadIdx.x;
    if (co >= COUT) return;
    u64 p[3];
    int nnz[3], ntot = 0;
    for (int k = 0; k < 3; ++k) {
        u64 pos = 0ull, nz = 0ull;
        for (int ci = 0; ci < CIN; ++ci) {
            float wv = w[co * (CIN * 3) + ci * 3 + k];
            pos |= ((u64)(wv > 0.0f)) << ci;
            nz  |= ((u64)(wv != 0.0f)) << ci;
        }
        p[k] = pos;
        nnz[k] = __popcll(nz);
        ntot += nnz[k];
    }
    WRec r;
    float s = wscale[co];
    r.p0 = p[0]; r.p1 = p[1]; r.p2 = p[2];
    r.A  = s * (float)ntot + bias[co];
    r.S  = -2.0f * s;
    r.Bv = beta[co]; r.G = gamma[co]; r.Z = zeta[co];
    r.f0 = 0.5f * (float)nnz[0];
    r.f2 = 0.5f * (float)nnz[2];
    r.pad[0] = r.pad[1] = r.pad[2] = 0.0f;
    rec[co] = r;
}

// ---------------------------------------------------------------------------
// Kernel A: streaming pack. 2048 blocks (8/CU, 32 waves/CU). Thread owns 2 l.
// Loads are register-batched 16-deep (no dependent ALU between them) so the
// VMEM pipe keeps ~16 requests in flight per wave; then pack, 16 B store.
// ---------------------------------------------------------------------------
__global__ void __launch_bounds__(256) pack_x(
        const float* __restrict__ x,
        const float* __restrict__ alpha,
        u64* __restrict__ bits) {
    const int t = threadIdx.x;
    const int b = blockIdx.y;
    const int l0 = blockIdx.x * 512 + 2 * t;
    const float* xb = x + (size_t)b * CIN * LLEN + l0;

    u64 w0 = 0, w1 = 0;
    #pragma unroll
    for (int q = 0; q < 4; ++q) {
        f32x2 buf[16];
        #pragma unroll
        for (int j = 0; j < 16; ++j)
            buf[j] = *(const f32x2*)(xb + (size_t)(q * 16 + j) * LLEN);
        #pragma unroll
        for (int j = 0; j < 16; ++j) {
            const int ci = q * 16 + j;
            const float a = alpha[ci];             // uniform -> s_load
            w0 |= ((u64)(buf[j].x >= a)) << ci;
            w1 |= ((u64)(buf[j].y >= a)) << ci;
        }
    }
    u64* dst = bits + (size_t)b * BROW + l0 + 1;   // 16 B contiguous per thread
    dst[0] = w0; dst[1] = w1;
}

__device__ __forceinline__ float rprelu(float y, float B, float G, float Z) {
    float xs = y - G;
    return (y > G) ? (xs + Z) : fmaf(B, xs, Z);
}

// ---------------------------------------------------------------------------
// Kernel B: compute + contiguous stream-out. Block = (co, chunk, b); writes
// out[b][co][c0 .. c0+8192) = 32 KB contiguous via nt f32x4. WRec fetched
// once per block (SGPRs). bits windows come from L2/L3 (8.4 MB, 64x reuse).
// Thread t handles l = c0 + 1024*j + 4*t for j=0..7 (lane-consecutive =
// address-consecutive within every store instruction).
// ---------------------------------------------------------------------------
__global__ void __launch_bounds__(256) bconv_compute(
        const u64* __restrict__ bits,
        const WRec* __restrict__ rec,
        float* __restrict__ out) {
    const int t     = threadIdx.x;
    const int co    = blockIdx.x;
    const int chunk = blockIdx.y;
    const int b     = blockIdx.z;
    const int c0    = chunk * 8192;

    const WRec r = rec[co];                        // uniform -> s_load_dwordx16
    const u64* bb = bits + (size_t)b * BROW + c0;
    float* outp = out + ((size_t)b * COUT + co) * LLEN + c0 + 4 * t;

    const bool lo = (chunk == 0) && (t == 0);              // contains l==0
    const bool hi = (chunk == 7) && (t == 255);            // contains l==LLEN-1

    #pragma unroll 4
    for (int j = 0; j < 8; ++j) {
        const int l0 = 1024 * j + 4 * t;
        const u64* src = bb + l0;                  // idx l0 -> word(c0+l0-1)
        const u64 xq0 = src[0], xq1 = src[1], xq2 = src[2],
                  xq3 = src[3], xq4 = src[4], xq5 = src[5];

        float fx = (float)(__popcll(xq0 ^ r.p0) + __popcll(xq1 ^ r.p1)
                         + __popcll(xq2 ^ r.p2));
        float fy = (float)(__popcll(xq1 ^ r.p0) + __popcll(xq2 ^ r.p1)
                         + __popcll(xq3 ^ r.p2));
        float fz = (float)(__popcll(xq2 ^ r.p0) + __popcll(xq3 ^ r.p1)
                         + __popcll(xq4 ^ r.p2));
        float fw = (float)(__popcll(xq3 ^ r.p0) + __popcll(xq4 ^ r.p1)
                         + __popcll(xq5 ^ r.p2));
        if (j == 0 && lo)   // l==0: k=0 term is zero padding
            fx = (float)(__popcll(xq1 ^ r.p1) + __popcll(xq2 ^ r.p2)) + r.f0;
        if (j == 7 && hi)   // l==LLEN-1: k=2 term is zero padding
            fw = (float)(__popcll(xq3 ^ r.p0) + __popcll(xq4 ^ r.p1)) + r.f2;

        f32x4 o;
        o.x = rprelu(fmaf(r.S, fx, r.A), r.Bv, r.G, r.Z);
        o.y = rprelu(fmaf(r.S, fy, r.A), r.Bv, r.G, r.Z);
        o.z = rprelu(fmaf(r.S, fz, r.A), r.Bv, r.G, r.Z);
        o.w = rprelu(fmaf(r.S, fw, r.A), r.Bv, r.G, r.Z);
        __builtin_nontemporal_store(o, (f32x4*)(outp + 1024 * j));
    }
}

extern "C" void kernel_launch(void* const* d_in, const int* in_sizes, int n_in,
                              void* d_out, int out_size, void* d_ws, size_t ws_size,
                              hipStream_t stream) {
    const float* x      = (const float*)d_in[0];
    const float* alpha  = (const float*)d_in[1];
    const float* w      = (const float*)d_in[2];
    const float* wscale = (const float*)d_in[3];
    const float* bias   = (const float*)d_in[4];
    const float* beta   = (const float*)d_in[5];
    const float* gamma  = (const float*)d_in[6];
    const float* zeta   = (const float*)d_in[7];
    float* out = (float*)d_out;

    // ws layout: [0, 4KB) WRec[64]; [4KB, 4KB + 16*BROW*8) packed bits.
    WRec* rec = (WRec*)d_ws;
    u64* bits = (u64*)((char*)d_ws + 4096);

    pack_weights<<<1, 64, 0, stream>>>(w, wscale, bias, beta, gamma, zeta, rec);

    dim3 gridA(LLEN / 512, 16);
    pack_x<<<gridA, 256, 0, stream>>>(x, alpha, bits);

    dim3 gridB(COUT, 8, 16);   // (co, chunk, b) — co innermost for bits L2 reuse
    bconv_compute<<<gridB, 256, 0, stream>>>(bits, rec, out);
}

// Round 13
// 103.581 us; speedup vs baseline: 1.3545x; 1.0126x over previous
//
#include <hip/hip_runtime.h>

#define LLEN 65536
#define CIN 64
#define COUT 64
// bits row: word(l) stored at position l+4; rows (LLEN+8) u64 = 32B-aligned.
// Positions 0..3 and LLEN+4..LLEN+7 are never written (EDGE fixups ignore).
#define BROW (LLEN + 8)

typedef float f32x4 __attribute__((ext_vector_type(4)));
typedef unsigned long long u64;
typedef u64 u64x4 __attribute__((ext_vector_type(4)));

// Per-co constant record, 64 B so the per-block fetch is one s_load_dwordx16.
struct __align__(64) WRec {
    u64 p0, p1, p2;                 // sign words (bit=1 iff w>0) for k=0,1,2
    float A;    // wscale * sum_nnz + bias
    float S;    // -2 * wscale
    float Bv, G, Z;                 // RPReLU beta, gamma, zeta
    float f0, f2;                   // 0.5*nnz(k=0), 0.5*nnz(k=2) edge fixups
    float pad[3];
};

// ---------------------------------------------------------------------------
// pack_weights: one wave, thread = co. w[co] is 192 CONTIGUOUS floats ->
// 48 f32x4 loads batched 12-deep; (ci,k) decode is compile-time (full unroll).
// Was: 192 strided scalar loads latency-chained (~5-10 us serial tail).
// ---------------------------------------------------------------------------
__global__ void pack_weights(const float* __restrict__ w,
                             const float* __restrict__ wscale,
                             const float* __restrict__ bias,
                             const float* __restrict__ beta,
                             const float* __restrict__ gamma,
                             const float* __restrict__ zeta,
                             WRec* __restrict__ rec) {
    int co = threadIdx.x;
    if (co >= COUT) return;
    const float* wr = w + co * (CIN * 3);
    u64 p[3] = {0, 0, 0}, nzw[3] = {0, 0, 0};
    #pragma unroll
    for (int q = 0; q < 4; ++q) {
        f32x4 buf[12];
        #pragma unroll
        for (int j = 0; j < 12; ++j)
            buf[j] = *(const f32x4*)(wr + q * 48 + 4 * j);
        #pragma unroll
        for (int j = 0; j < 12; ++j) {
            #pragma unroll
            for (int m = 0; m < 4; ++m) {
                const int idx = q * 48 + 4 * j + m;   // compile-time constant
                const int ci = idx / 3, k = idx % 3;
                const float wv = buf[j][m];
                p[k]   |= ((u64)(wv > 0.0f)) << ci;
                nzw[k] |= ((u64)(wv != 0.0f)) << ci;
            }
        }
    }
    const int n0 = __popcll(nzw[0]), n1 = __popcll(nzw[1]), n2 = __popcll(nzw[2]);
    WRec r;
    float s = wscale[co];
    r.p0 = p[0]; r.p1 = p[1]; r.p2 = p[2];
    r.A  = s * (float)(n0 + n1 + n2) + bias[co];
    r.S  = -2.0f * s;
    r.Bv = beta[co]; r.G = gamma[co]; r.Z = zeta[co];
    r.f0 = 0.5f * (float)n0;
    r.f2 = 0.5f * (float)n2;
    r.pad[0] = r.pad[1] = r.pad[2] = 0.0f;
    rec[co] = r;
}

// ---------------------------------------------------------------------------
// Kernel A: streaming pack. Thread owns 4 l; 64 f32x4 reads batched 8-deep
// (no dependent ALU between batch loads -> ~8 reqs in flight/wave), then one
// aligned 32 B bits store. Grid 1024 blocks.
// ---------------------------------------------------------------------------
__global__ void __launch_bounds__(256) pack_x(
        const float* __restrict__ x,
        const float* __restrict__ alpha,
        u64* __restrict__ bits) {
    const int t = threadIdx.x;
    const int b = blockIdx.y;
    const int l0 = blockIdx.x * 1024 + 4 * t;
    const float* xb = x + (size_t)b * CIN * LLEN + l0;

    u64 w0 = 0, w1 = 0, w2 = 0, w3 = 0;
    #pragma unroll
    for (int q = 0; q < 8; ++q) {
        f32x4 buf[8];
        #pragma unroll
        for (int j = 0; j < 8; ++j)
            buf[j] = *(const f32x4*)(xb + (size_t)(q * 8 + j) * LLEN);
        #pragma unroll
        for (int j = 0; j < 8; ++j) {
            const int ci = q * 8 + j;
            const float a = alpha[ci];             // uniform -> s_load
            w0 |= ((u64)(buf[j].x >= a)) << ci;
            w1 |= ((u64)(buf[j].y >= a)) << ci;
            w2 |= ((u64)(buf[j].z >= a)) << ci;
            w3 |= ((u64)(buf[j].w >= a)) << ci;
        }
    }
    // word(l) at position l+4; (l0+4)*8 is 32B-aligned (l0 multiple of 4).
    u64x4 v; v.x = w0; v.y = w1; v.z = w2; v.w = w3;
    *(u64x4*)(bits + (size_t)b * BROW + l0 + 4) = v;
}

__device__ __forceinline__ float rprelu(float y, float B, float G, float Z) {
    float xs = y - G;
    return (y > G) ? (xs + Z) : fmaf(B, xs, Z);
}

// ---------------------------------------------------------------------------
// Kernel B: compute + contiguous stream-out. Block = (co, chunk, b); writes
// out[b][co][c0 .. c0+8192) = 32 KB contiguous via nt f32x4. WRec fetched
// once per block (SGPRs). bits windows come from L2/L3 (8.4 MB, 64x reuse).
// Window for l: word(l-1)..word(l+4) = positions (l+3)..(l+8).
// ---------------------------------------------------------------------------
__global__ void __launch_bounds__(256) bconv_compute(
        const u64* __restrict__ bits,
        const WRec* __restrict__ rec,
        float* __restrict__ out) {
    const int t     = threadIdx.x;
    const int co    = blockIdx.x;
    const int chunk = blockIdx.y;
    const int b     = blockIdx.z;
    const int c0    = chunk * 8192;

    const WRec r = rec[co];                        // uniform -> s_load_dwordx16
    const u64* base = bits + (size_t)b * BROW + c0 + 4 * t;
    float* outp = out + ((size_t)b * COUT + co) * LLEN + c0 + 4 * t;

    const bool lo = (chunk == 0) && (t == 0);              // contains l==0
    const bool hi = (chunk == 7) && (t == 255);            // contains l==LLEN-1

    #pragma unroll 4
    for (int j = 0; j < 8; ++j) {
        const u64* src = base + 1024 * j;
        const u64 xq0 = src[3], xq1 = src[4], xq2 = src[5],
                  xq3 = src[6], xq4 = src[7], xq5 = src[8];

        float fx = (float)(__popcll(xq0 ^ r.p0) + __popcll(xq1 ^ r.p1)
                         + __popcll(xq2 ^ r.p2));
        float fy = (float)(__popcll(xq1 ^ r.p0) + __popcll(xq2 ^ r.p1)
                         + __popcll(xq3 ^ r.p2));
        float fz = (float)(__popcll(xq2 ^ r.p0) + __popcll(xq3 ^ r.p1)
                         + __popcll(xq4 ^ r.p2));
        float fw = (float)(__popcll(xq3 ^ r.p0) + __popcll(xq4 ^ r.p1)
                         + __popcll(xq5 ^ r.p2));
        if (j == 0 && lo)   // l==0: k=0 term is zero padding
            fx = (float)(__popcll(xq1 ^ r.p1) + __popcll(xq2 ^ r.p2)) + r.f0;
        if (j == 7 && hi)   // l==LLEN-1: k=2 term is zero padding
            fw = (float)(__popcll(xq3 ^ r.p0) + __popcll(xq4 ^ r.p1)) + r.f2;

        f32x4 o;
        o.x = rprelu(fmaf(r.S, fx, r.A), r.Bv, r.G, r.Z);
        o.y = rprelu(fmaf(r.S, fy, r.A), r.Bv, r.G, r.Z);
        o.z = rprelu(fmaf(r.S, fz, r.A), r.Bv, r.G, r.Z);
        o.w = rprelu(fmaf(r.S, fw, r.A), r.Bv, r.G, r.Z);
        __builtin_nontemporal_store(o, (f32x4*)(outp + 1024 * j));
    }
}

extern "C" void kernel_launch(void* const* d_in, const int* in_sizes, int n_in,
                              void* d_out, int out_size, void* d_ws, size_t ws_size,
                              hipStream_t stream) {
    const float* x      = (const float*)d_in[0];
    const float* alpha  = (const float*)d_in[1];
    const float* w      = (const float*)d_in[2];
    const float* wscale = (const float*)d_in[3];
    const float* bias   = (const float*)d_in[4];
    const float* beta   = (const float*)d_in[5];
    const float* gamma  = (const float*)d_in[6];
    const float* zeta   = (const float*)d_in[7];
    float* out = (float*)d_out;

    // ws layout: [0, 4KB) WRec[64]; [4KB, 4KB + 16*BROW*8) packed bits.
    WRec* rec = (WRec*)d_ws;
    u64* bits = (u64*)((char*)d_ws + 4096);

    pack_weights<<<1, 64, 0, stream>>>(w, wscale, bias, beta, gamma, zeta, rec);

    dim3 gridA(LLEN / 1024, 16);
    pack_x<<<gridA, 256, 0, stream>>>(x, alpha, bits);

    dim3 gridB(COUT, 8, 16);   // (co, chunk, b) — co innermost for bits L2 reuse
    bconv_compute<<<gridB, 256, 0, stream>>>(bits, rec, out);
}

// Round 14
// 102.617 us; speedup vs baseline: 1.3672x; 1.0094x over previous
//
#include <hip/hip_runtime.h>

#define LLEN 65536
#define CIN 64
#define COUT 64
// bits row: word(l) stored at position l+4; rows (LLEN+8) u64 = 32B-aligned.
// Positions 0..3 and LLEN+4..LLEN+7 are never written (EDGE fixups ignore).
#define BROW (LLEN + 8)
#define NBLK_A (LLEN / 2048)   // 32 data blocks per batch row

typedef float f32x4 __attribute__((ext_vector_type(4)));
typedef unsigned long long u64;
typedef u64 u64x4 __attribute__((ext_vector_type(4)));

// Per-co constant record, 64 B so the per-block fetch is one s_load_dwordx16.
struct __align__(64) WRec {
    u64 p0, p1, p2;                 // sign words (bit=1 iff w>0) for k=0,1,2
    float A;    // wscale * sum_nnz + bias
    float S;    // -2 * wscale
    float Bv, G, Z;                 // RPReLU beta, gamma, zeta
    float f0, f2;                   // 0.5*nnz(k=0), 0.5*nnz(k=2) edge fixups
    float pad[3];
};

__device__ __forceinline__ void pack_weights_body(
        const float* __restrict__ w, const float* __restrict__ wscale,
        const float* __restrict__ bias, const float* __restrict__ beta,
        const float* __restrict__ gamma, const float* __restrict__ zeta,
        WRec* __restrict__ rec) {
    int co = threadIdx.x;
    if (co >= COUT) return;
    const float* wr = w + co * (CIN * 3);
    u64 p[3] = {0, 0, 0}, nzw[3] = {0, 0, 0};
    #pragma unroll
    for (int q = 0; q < 4; ++q) {
        f32x4 buf[12];
        #pragma unroll
        for (int j = 0; j < 12; ++j)
            buf[j] = *(const f32x4*)(wr + q * 48 + 4 * j);
        #pragma unroll
        for (int j = 0; j < 12; ++j) {
            #pragma unroll
            for (int m = 0; m < 4; ++m) {
                const int idx = q * 48 + 4 * j + m;   // compile-time constant
                const int ci = idx / 3, k = idx % 3;
                const float wv = buf[j][m];
                p[k]   |= ((u64)(wv > 0.0f)) << ci;
                nzw[k] |= ((u64)(wv != 0.0f)) << ci;
            }
        }
    }
    const int n0 = __popcll(nzw[0]), n1 = __popcll(nzw[1]), n2 = __popcll(nzw[2]);
    WRec r;
    float s = wscale[co];
    r.p0 = p[0]; r.p1 = p[1]; r.p2 = p[2];
    r.A  = s * (float)(n0 + n1 + n2) + bias[co];
    r.S  = -2.0f * s;
    r.Bv = beta[co]; r.G = gamma[co]; r.Z = zeta[co];
    r.f0 = 0.5f * (float)n0;
    r.f2 = 0.5f * (float)n2;
    r.pad[0] = r.pad[1] = r.pad[2] = 0.0f;
    rec[co] = r;
}

// ---------------------------------------------------------------------------
// Kernel A: streaming pack. Block = (2048-l tile, b) -> per-ci segment is
// 8 KB (half the stream count of R13's 4 KB). Thread owns 8 l as two 16 B
// lanes-coalesced f32x4 loads per row (at +4t and +1024+4t), nontemporal
// (x is read-once; keep L3 clean). Loads batched 4 rows x 2 = 8 in flight.
// Extra block (blockIdx.x == NBLK_A, y == 0) packs the weights -> no
// separate serial launch.
// ---------------------------------------------------------------------------
__global__ void __launch_bounds__(256) pack_x(
        const float* __restrict__ x,
        const float* __restrict__ alpha,
        u64* __restrict__ bits,
        const float* __restrict__ w,
        const float* __restrict__ wscale,
        const float* __restrict__ bias,
        const float* __restrict__ beta,
        const float* __restrict__ gamma,
        const float* __restrict__ zeta,
        WRec* __restrict__ rec) {
    if (blockIdx.x == NBLK_A) {
        if (blockIdx.y == 0)
            pack_weights_body(w, wscale, bias, beta, gamma, zeta, rec);
        return;
    }
    const int t = threadIdx.x;
    const int b = blockIdx.y;
    const int l0 = blockIdx.x * 2048;
    const float* xb = x + (size_t)b * CIN * LLEN + l0 + 4 * t;

    u64 wa0 = 0, wa1 = 0, wa2 = 0, wa3 = 0;   // words for l0+4t..+3
    u64 wb0 = 0, wb1 = 0, wb2 = 0, wb3 = 0;   // words for l0+1024+4t..+3
    #pragma unroll
    for (int q = 0; q < 16; ++q) {
        f32x4 blo[4], bhi[4];
        #pragma unroll
        for (int j = 0; j < 4; ++j) {
            const float* rp = xb + (size_t)(q * 4 + j) * LLEN;
            blo[j] = __builtin_nontemporal_load((const f32x4*)rp);
            bhi[j] = __builtin_nontemporal_load((const f32x4*)(rp + 1024));
        }
        #pragma unroll
        for (int j = 0; j < 4; ++j) {
            const int ci = q * 4 + j;
            const float a = alpha[ci];             // uniform -> s_load
            wa0 |= ((u64)(blo[j].x >= a)) << ci;
            wa1 |= ((u64)(blo[j].y >= a)) << ci;
            wa2 |= ((u64)(blo[j].z >= a)) << ci;
            wa3 |= ((u64)(blo[j].w >= a)) << ci;
            wb0 |= ((u64)(bhi[j].x >= a)) << ci;
            wb1 |= ((u64)(bhi[j].y >= a)) << ci;
            wb2 |= ((u64)(bhi[j].z >= a)) << ci;
            wb3 |= ((u64)(bhi[j].w >= a)) << ci;
        }
    }
    // word(l) at position l+4; (l0+4t+4) is a multiple of 4 -> 32 B aligned.
    u64* dst = bits + (size_t)b * BROW + l0 + 4 * t + 4;
    u64x4 va; va.x = wa0; va.y = wa1; va.z = wa2; va.w = wa3;
    u64x4 vb; vb.x = wb0; vb.y = wb1; vb.z = wb2; vb.w = wb3;
    *(u64x4*)dst = va;
    *(u64x4*)(dst + 1024) = vb;
}

__device__ __forceinline__ float rprelu(float y, float B, float G, float Z) {
    float xs = y - G;
    return (y > G) ? (xs + Z) : fmaf(B, xs, Z);
}

// ---------------------------------------------------------------------------
// Kernel B: compute + contiguous stream-out. Block = (chunk, co, b) with
// chunk INNERMOST: consecutive blocks write consecutive 32 KB -> sequential
// 256 KB write runs per (co,b). WRec fetched once per block (SGPRs). bits
// row (528 KB) stays L2-resident across the 64-co sweep.
// Window for l: word(l-1)..word(l+4) = positions (l+3)..(l+8).
// ---------------------------------------------------------------------------
__global__ void __launch_bounds__(256) bconv_compute(
        const u64* __restrict__ bits,
        const WRec* __restrict__ rec,
        float* __restrict__ out) {
    const int t     = threadIdx.x;
    const int chunk = blockIdx.x;
    const int co    = blockIdx.y;
    const int b     = blockIdx.z;
    const int c0    = chunk * 8192;

    const WRec r = rec[co];                        // uniform -> s_load_dwordx16
    const u64* base = bits + (size_t)b * BROW + c0 + 4 * t;
    float* outp = out + ((size_t)b * COUT + co) * LLEN + c0 + 4 * t;

    const bool lo = (chunk == 0) && (t == 0);              // contains l==0
    const bool hi = (chunk == 7) && (t == 255);            // contains l==LLEN-1

    #pragma unroll 4
    for (int j = 0; j < 8; ++j) {
        const u64* src = base + 1024 * j;
        const u64 xq0 = src[3], xq1 = src[4], xq2 = src[5],
                  xq3 = src[6], xq4 = src[7], xq5 = src[8];

        float fx = (float)(__popcll(xq0 ^ r.p0) + __popcll(xq1 ^ r.p1)
                         + __popcll(xq2 ^ r.p2));
        float fy = (float)(__popcll(xq1 ^ r.p0) + __popcll(xq2 ^ r.p1)
                         + __popcll(xq3 ^ r.p2));
        float fz = (float)(__popcll(xq2 ^ r.p0) + __popcll(xq3 ^ r.p1)
                         + __popcll(xq4 ^ r.p2));
        float fw = (float)(__popcll(xq3 ^ r.p0) + __popcll(xq4 ^ r.p1)
                         + __popcll(xq5 ^ r.p2));
        if (j == 0 && lo)   // l==0: k=0 term is zero padding
            fx = (float)(__popcll(xq1 ^ r.p1) + __popcll(xq2 ^ r.p2)) + r.f0;
        if (j == 7 && hi)   // l==LLEN-1: k=2 term is zero padding
            fw = (float)(__popcll(xq3 ^ r.p0) + __popcll(xq4 ^ r.p1)) + r.f2;

        f32x4 o;
        o.x = rprelu(fmaf(r.S, fx, r.A), r.Bv, r.G, r.Z);
        o.y = rprelu(fmaf(r.S, fy, r.A), r.Bv, r.G, r.Z);
        o.z = rprelu(fmaf(r.S, fz, r.A), r.Bv, r.G, r.Z);
        o.w = rprelu(fmaf(r.S, fw, r.A), r.Bv, r.G, r.Z);
        __builtin_nontemporal_store(o, (f32x4*)(outp + 1024 * j));
    }
}

extern "C" void kernel_launch(void* const* d_in, const int* in_sizes, int n_in,
                              void* d_out, int out_size, void* d_ws, size_t ws_size,
                              hipStream_t stream) {
    const float* x      = (const float*)d_in[0];
    const float* alpha  = (const float*)d_in[1];
    const float* w      = (const float*)d_in[2];
    const float* wscale = (const float*)d_in[3];
    const float* bias   = (const float*)d_in[4];
    const float* beta   = (const float*)d_in[5];
    const float* gamma  = (const float*)d_in[6];
    const float* zeta   = (const float*)d_in[7];
    float* out = (float*)d_out;

    // ws layout: [0, 4KB) WRec[64]; [4KB, 4KB + 16*BROW*8) packed bits.
    WRec* rec = (WRec*)d_ws;
    u64* bits = (u64*)((char*)d_ws + 4096);

    dim3 gridA(NBLK_A + 1, 16);   // +1: weights block
    pack_x<<<gridA, 256, 0, stream>>>(x, alpha, bits, w, wscale, bias,
                                      beta, gamma, zeta, rec);

    dim3 gridB(8, COUT, 16);   // (chunk, co, b) — chunk inner: sequential writes
    bconv_compute<<<gridB, 256, 0, stream>>>(bits, rec, out);
}